// Round 1
// baseline (839.290 us; speedup 1.0000x reference)
//
#include <hip/hip_runtime.h>
#include <cstdint>
#include <cstddef>

#define S_DIM 4096
#define B_DIM 32
#define H_DIM 512
#define M_DIM (S_DIM * B_DIM)

typedef unsigned short u16;
typedef unsigned int u32;
typedef float f32x4 __attribute__((ext_vector_type(4)));
typedef __bf16 bf16x8 __attribute__((ext_vector_type(8)));

__device__ __forceinline__ u16 f2bf(float v) {
    union { float f; u32 u; } a; a.f = v;
    u32 r = a.u + 0x7fffu + ((a.u >> 16) & 1u);   // RNE
    return (u16)(r >> 16);
}
__device__ __forceinline__ float bf2f(u16 b) {
    union { float f; u32 u; } a; a.u = ((u32)b) << 16; return a.f;
}
__device__ __forceinline__ void split_bf(float v, u16& h, u16& l) {
    h = f2bf(v);
    l = f2bf(v - bf2f(h));
}

// ---------------------------------------------------------------------------
// Kernel 1: split W (fp32 [H,H], row-major j,k) into bf16 hi/lo pair.
// ---------------------------------------------------------------------------
__global__ void prep_w(const float* __restrict__ W,
                       u16* __restrict__ Wh, u16* __restrict__ Wl) {
    int i = blockIdx.x * 256 + threadIdx.x;       // grid 1024 -> 262144 elems
    float w = W[i];
    u16 h, l;
    split_bf(w, h, l);
    Wh[i] = h; Wl[i] = l;
}

// ---------------------------------------------------------------------------
// Kernel 2: fused GEMM + epilogue reduction.
//   v[m,k] = enc[m,k] * hid[m%32, k]        (computed during staging, split hi/lo)
//   C[m,j] = sum_k v[m,k] * W[j,k]          (bf16x3 MFMA, fp32 accum)
//   L[m]   = sum_j enc[m-32, j] * C[m,j]    (fp32 epilogue, m >= 32)
// Block: 128 rows x (4 j-tiles of 128), BK=64, 4 waves each 64x64.
// ---------------------------------------------------------------------------
__global__ __launch_bounds__(256, 2) void bigram_gemm(
    const float* __restrict__ enc,
    const float* __restrict__ hid,
    const u16* __restrict__ Wh,
    const u16* __restrict__ Wl,
    float* __restrict__ L)
{
    constexpr int LDA = 72;                       // 64 + 8 pad (shorts)
    __shared__ u16 sAh[128 * LDA];
    __shared__ u16 sAl[128 * LDA];
    __shared__ u16 sBh[128 * LDA];
    __shared__ u16 sBl[128 * LDA];
    __shared__ float rowsum[2][128];

    const int tid  = threadIdx.x;
    const int wave = tid >> 6;
    const int lane = tid & 63;
    const int wr   = wave >> 1;                   // wave row (0..1) -> 64 rows
    const int wc   = wave & 1;                    // wave col (0..1) -> 64 cols
    const int m0   = blockIdx.x * 128;

    if (tid < 128) { rowsum[0][tid] = 0.f; rowsum[1][tid] = 0.f; }

    const int g    = lane >> 4;                   // quad 0..3
    const int cl   = lane & 15;
    const int koff = g * 8;                       // shorts

    for (int jt = 0; jt < 4; ++jt) {
        const int j0 = jt * 128;
        f32x4 acc[4][4];
        #pragma unroll
        for (int mf = 0; mf < 4; ++mf)
            #pragma unroll
            for (int nf = 0; nf < 4; ++nf)
                acc[mf][nf] = (f32x4){0.f, 0.f, 0.f, 0.f};

        for (int kt = 0; kt < 8; ++kt) {
            const int k0 = kt * 64;
            __syncthreads();
            // ---- stage A: compute v = enc*h, split hi/lo -> LDS ----
            #pragma unroll
            for (int i = 0; i < 8; ++i) {
                int chunk = tid + i * 256;        // 0..2047
                int r  = chunk >> 4;              // 0..127
                int c4 = (chunk & 15) << 2;       // 0..60
                int gm = m0 + r;
                const float4 e  = *(const float4*)(enc + (size_t)gm * H_DIM + k0 + c4);
                const float4 hv = *(const float4*)(hid + (size_t)(gm & 31) * H_DIM + k0 + c4);
                float v0 = e.x * hv.x, v1 = e.y * hv.y, v2 = e.z * hv.z, v3 = e.w * hv.w;
                u16 h0,h1,h2,h3,l0,l1,l2,l3;
                split_bf(v0, h0, l0); split_bf(v1, h1, l1);
                split_bf(v2, h2, l2); split_bf(v3, h3, l3);
                uint2 hw, lw;
                hw.x = (u32)h0 | ((u32)h1 << 16); hw.y = (u32)h2 | ((u32)h3 << 16);
                lw.x = (u32)l0 | ((u32)l1 << 16); lw.y = (u32)l2 | ((u32)l3 << 16);
                *(uint2*)(sAh + r * LDA + c4) = hw;
                *(uint2*)(sAl + r * LDA + c4) = lw;
            }
            // ---- stage B: copy Wh/Wl tiles (16B chunks) ----
            #pragma unroll
            for (int i = 0; i < 4; ++i) {
                int chunk = tid + i * 256;        // 0..1023
                int r  = chunk >> 3;              // 0..127
                int c8 = (chunk & 7) << 3;        // 0..56 shorts
                int gj = j0 + r;
                *(uint4*)(sBh + r * LDA + c8) = *(const uint4*)(Wh + (size_t)gj * H_DIM + k0 + c8);
                *(uint4*)(sBl + r * LDA + c8) = *(const uint4*)(Wl + (size_t)gj * H_DIM + k0 + c8);
            }
            __syncthreads();
            // ---- MFMA: 2 K-steps of 32, bf16x3 split ----
            #pragma unroll
            for (int kk = 0; kk < 2; ++kk) {
                const int kb = kk * 32 + koff;
                bf16x8 ah[4], al[4], bh[4], bl[4];
                #pragma unroll
                for (int mf = 0; mf < 4; ++mf) {
                    int row = wr * 64 + mf * 16 + cl;
                    ah[mf] = *(const bf16x8*)(sAh + row * LDA + kb);
                    al[mf] = *(const bf16x8*)(sAl + row * LDA + kb);
                }
                #pragma unroll
                for (int nf = 0; nf < 4; ++nf) {
                    int row = wc * 64 + nf * 16 + cl;
                    bh[nf] = *(const bf16x8*)(sBh + row * LDA + kb);
                    bl[nf] = *(const bf16x8*)(sBl + row * LDA + kb);
                }
                #pragma unroll
                for (int mf = 0; mf < 4; ++mf)
                    #pragma unroll
                    for (int nf = 0; nf < 4; ++nf) {
                        acc[mf][nf] = __builtin_amdgcn_mfma_f32_16x16x32_bf16(ah[mf], bh[nf], acc[mf][nf], 0, 0, 0);
                        acc[mf][nf] = __builtin_amdgcn_mfma_f32_16x16x32_bf16(ah[mf], bl[nf], acc[mf][nf], 0, 0, 0);
                        acc[mf][nf] = __builtin_amdgcn_mfma_f32_16x16x32_bf16(al[mf], bh[nf], acc[mf][nf], 0, 0, 0);
                    }
            }
        }
        // ---- epilogue: L_partial[row] += sum_col encprev[row-32, col] * C ----
        #pragma unroll
        for (int mf = 0; mf < 4; ++mf) {
            float rs0 = 0.f, rs1 = 0.f, rs2 = 0.f, rs3 = 0.f;
            const int growb = m0 + wr * 64 + mf * 16 + g * 4;
            #pragma unroll
            for (int nf = 0; nf < 4; ++nf) {
                const int gcol = j0 + wc * 64 + nf * 16 + cl;
                float e0 = (growb + 0 >= B_DIM) ? enc[(size_t)(growb + 0 - B_DIM) * H_DIM + gcol] : 0.f;
                float e1 = (growb + 1 >= B_DIM) ? enc[(size_t)(growb + 1 - B_DIM) * H_DIM + gcol] : 0.f;
                float e2 = (growb + 2 >= B_DIM) ? enc[(size_t)(growb + 2 - B_DIM) * H_DIM + gcol] : 0.f;
                float e3 = (growb + 3 >= B_DIM) ? enc[(size_t)(growb + 3 - B_DIM) * H_DIM + gcol] : 0.f;
                rs0 += acc[mf][nf][0] * e0;
                rs1 += acc[mf][nf][1] * e1;
                rs2 += acc[mf][nf][2] * e2;
                rs3 += acc[mf][nf][3] * e3;
            }
            #pragma unroll
            for (int off = 1; off < 16; off <<= 1) {
                rs0 += __shfl_xor(rs0, off);
                rs1 += __shfl_xor(rs1, off);
                rs2 += __shfl_xor(rs2, off);
                rs3 += __shfl_xor(rs3, off);
            }
            if (cl == 0) {
                const int rb = wr * 64 + mf * 16 + g * 4;
                rowsum[wc][rb + 0] += rs0;
                rowsum[wc][rb + 1] += rs1;
                rowsum[wc][rb + 2] += rs2;
                rowsum[wc][rb + 3] += rs3;
            }
        }
    }
    __syncthreads();
    if (tid < 128) {
        int gm = m0 + tid;
        if (gm >= B_DIM) L[gm] = rowsum[0][tid] + rowsum[1][tid];
    }
}

// ---------------------------------------------------------------------------
// Kernel 3: per-b softmax over s, plus affect term and the s=0 logit.
// ---------------------------------------------------------------------------
__global__ __launch_bounds__(256) void softmax_kernel(
    const float* __restrict__ enc,
    const float* __restrict__ hid,
    const float* __restrict__ emb,
    const float* __restrict__ aff,
    const float* __restrict__ L,
    float* __restrict__ out)
{
    __shared__ float logits[S_DIM];
    __shared__ float wred[4][4];
    __shared__ float bcast[4];
    __shared__ float wtmp[4];

    const int b    = blockIdx.x;
    const int tid  = threadIdx.x;
    const int wave = tid >> 6;
    const int lane = tid & 63;

    // ha[k] = sum_h hid[b,h]*aff[h,k];  s0 = sum_h enc[0,b,h]*hid[b,h]
    float p0 = 0.f, p1 = 0.f, p2 = 0.f, p3 = 0.f;
    for (int h = tid; h < H_DIM; h += 256) {
        float hv = hid[b * H_DIM + h];
        p0 += hv * aff[h * 3 + 0];
        p1 += hv * aff[h * 3 + 1];
        p2 += hv * aff[h * 3 + 2];
        p3 += hv * enc[(size_t)b * H_DIM + h];
    }
    #pragma unroll
    for (int off = 32; off > 0; off >>= 1) {
        p0 += __shfl_down(p0, off);
        p1 += __shfl_down(p1, off);
        p2 += __shfl_down(p2, off);
        p3 += __shfl_down(p3, off);
    }
    if (lane == 0) { wred[wave][0] = p0; wred[wave][1] = p1; wred[wave][2] = p2; wred[wave][3] = p3; }
    __syncthreads();
    if (tid < 4) bcast[tid] = wred[0][tid] + wred[1][tid] + wred[2][tid] + wred[3][tid];
    __syncthreads();
    const float ha0 = bcast[0], ha1 = bcast[1], ha2 = bcast[2], s0dot = bcast[3];

    float mx = -3.4e38f;
    for (int s = tid; s < S_DIM; s += 256) {
        float ed = (s == 0) ? s0dot : L[s * B_DIM + b];
        const float* e = emb + (size_t)(s * B_DIM + b) * 3;
        float lg = ed + ha0 * e[0] + ha1 * e[1] + ha2 * e[2];
        logits[s] = lg;
        mx = fmaxf(mx, lg);
    }
    #pragma unroll
    for (int off = 32; off > 0; off >>= 1) mx = fmaxf(mx, __shfl_xor(mx, off));
    if (lane == 0) wtmp[wave] = mx;
    __syncthreads();
    mx = fmaxf(fmaxf(wtmp[0], wtmp[1]), fmaxf(wtmp[2], wtmp[3]));
    __syncthreads();

    float sum = 0.f;
    for (int s = tid; s < S_DIM; s += 256) {
        float ex = __expf(logits[s] - mx);
        logits[s] = ex;
        sum += ex;
    }
    #pragma unroll
    for (int off = 32; off > 0; off >>= 1) sum += __shfl_xor(sum, off);
    if (lane == 0) wtmp[wave] = sum;
    __syncthreads();
    sum = wtmp[0] + wtmp[1] + wtmp[2] + wtmp[3];
    const float inv = 1.0f / sum;
    for (int s = tid; s < S_DIM; s += 256) {
        out[(size_t)b * S_DIM + s] = logits[s] * inv;
    }
}

// ---------------------------------------------------------------------------
extern "C" void kernel_launch(void* const* d_in, const int* in_sizes, int n_in,
                              void* d_out, int out_size, void* d_ws, size_t ws_size,
                              hipStream_t stream) {
    const float* hid = (const float*)d_in[0];   // [1,B,H]
    const float* enc = (const float*)d_in[1];   // [S,B,H]
    const float* emb = (const float*)d_in[2];   // [S,B,3]
    const float* Wm  = (const float*)d_in[3];   // [H,H]
    const float* aff = (const float*)d_in[4];   // [H,3]
    float* out = (float*)d_out;                 // [B,1,S]

    char* ws = (char*)d_ws;
    u16*   Wh = (u16*)(ws);                     // 512 KB
    u16*   Wl = (u16*)(ws + (512u << 10));      // 512 KB
    float* L  = (float*)(ws + (1024u << 10));   // 512 KB (logit e_dot, m-order)

    hipLaunchKernelGGL(prep_w,         dim3(1024), dim3(256), 0, stream, Wm, Wh, Wl);
    hipLaunchKernelGGL(bigram_gemm,    dim3(1024), dim3(256), 0, stream, enc, hid, Wh, Wl, L);
    hipLaunchKernelGGL(softmax_kernel, dim3(32),   dim3(256), 0, stream, enc, hid, emb, aff, L, out);
}

// Round 2
// 835.921 us; speedup vs baseline: 1.0040x; 1.0040x over previous
//
#include <hip/hip_runtime.h>
#include <cstdint>
#include <cstddef>

#define S_DIM 4096
#define B_DIM 32
#define H_DIM 512
#define M_DIM (S_DIM * B_DIM)

typedef unsigned short u16;
typedef unsigned int u32;
typedef float f32x4 __attribute__((ext_vector_type(4)));
typedef __bf16 bf16x8 __attribute__((ext_vector_type(8)));

__device__ __forceinline__ u16 f2bf(float v) {
    union { float f; u32 u; } a; a.f = v;
    u32 r = a.u + 0x7fffu + ((a.u >> 16) & 1u);   // RNE
    return (u16)(r >> 16);
}
__device__ __forceinline__ float bf2f(u16 b) {
    union { float f; u32 u; } a; a.u = ((u32)b) << 16; return a.f;
}
__device__ __forceinline__ void split_bf(float v, u16& h, u16& l) {
    h = f2bf(v);
    l = f2bf(v - bf2f(h));
}

// ---------------------------------------------------------------------------
// Kernel 1: split W (fp32 [H,H], row-major j,k) into bf16 hi/lo pair.
// ---------------------------------------------------------------------------
__global__ void prep_w(const float* __restrict__ W,
                       u16* __restrict__ Wh, u16* __restrict__ Wl) {
    int i = blockIdx.x * 256 + threadIdx.x;       // grid 1024 -> 262144 elems
    float w = W[i];
    u16 h, l;
    split_bf(w, h, l);
    Wh[i] = h; Wl[i] = l;
}

// ---------------------------------------------------------------------------
// Kernel 2: barrier-free fused GEMM + epilogue reduction.
//   v[m,k] = enc[m,k] * hid[m%32, k]   (loaded+split in registers, once)
//   C[m,j] = sum_k v[m,k] * W[j,k]     (bf16x3 MFMA, fp32 accum)
//   L[m]   = sum_j enc[m-32, j] * C[m,j]
// kt outer (A frags live across jt), jt inner with acc reset + partial
// epilogue per (kt,jt). No LDS staging, no mid-loop barriers.
// Output L stored TRANSPOSED: L[b*S + s] for coalesced softmax reads.
// ---------------------------------------------------------------------------
__global__ __launch_bounds__(256, 2) void bigram_gemm(
    const float* __restrict__ enc,
    const float* __restrict__ hid,
    const u16* __restrict__ Wh,
    const u16* __restrict__ Wl,
    float* __restrict__ L)
{
    __shared__ float rowsum[2][128];

    const int tid  = threadIdx.x;
    const int wave = tid >> 6;
    const int lane = tid & 63;
    const int wr   = wave >> 1;                   // wave row (0..1) -> 64 rows
    const int wc   = wave & 1;                    // wave col (0..1) -> 256 cols
    const int m0   = blockIdx.x * 128;

    const int g    = lane >> 4;                   // quad 0..3
    const int cl   = lane & 15;

    if (tid < 128) { rowsum[0][tid] = 0.f; rowsum[1][tid] = 0.f; }
    __syncthreads();

    for (int kt = 0; kt < 8; ++kt) {
        // ---- A fragments: direct global load + multiply + split ----
        bf16x8 ah[4][2], al[4][2];
        #pragma unroll
        for (int kk = 0; kk < 2; ++kk) {
            const int k0 = kt * 64 + kk * 32 + g * 8;
            // hid rows: mf even -> cl, mf odd -> cl+16 (m0,wr*64 are %32==0)
            const float4 hA0 = *(const float4*)(hid + (size_t)cl * H_DIM + k0);
            const float4 hA1 = *(const float4*)(hid + (size_t)cl * H_DIM + k0 + 4);
            const float4 hB0 = *(const float4*)(hid + (size_t)(cl + 16) * H_DIM + k0);
            const float4 hB1 = *(const float4*)(hid + (size_t)(cl + 16) * H_DIM + k0 + 4);
            #pragma unroll
            for (int mf = 0; mf < 4; ++mf) {
                const size_t rbase = (size_t)(m0 + wr * 64 + mf * 16 + cl) * H_DIM + k0;
                const float4 e0 = *(const float4*)(enc + rbase);
                const float4 e1 = *(const float4*)(enc + rbase + 4);
                const float4 h0 = (mf & 1) ? hB0 : hA0;
                const float4 h1 = (mf & 1) ? hB1 : hA1;
                float v[8];
                v[0] = e0.x * h0.x; v[1] = e0.y * h0.y; v[2] = e0.z * h0.z; v[3] = e0.w * h0.w;
                v[4] = e1.x * h1.x; v[5] = e1.y * h1.y; v[6] = e1.z * h1.z; v[7] = e1.w * h1.w;
                union { bf16x8 v8; u16 s[8]; } Hi, Lo;
                #pragma unroll
                for (int i = 0; i < 8; ++i) split_bf(v[i], Hi.s[i], Lo.s[i]);
                ah[mf][kk] = Hi.v8;
                al[mf][kk] = Lo.v8;
            }
        }

        // ---- j tiles: B frags from L2, MFMA, partial epilogue ----
        for (int jt = 0; jt < 4; ++jt) {
            const int j0 = jt * 128;
            f32x4 acc[4][4];
            #pragma unroll
            for (int mf = 0; mf < 4; ++mf)
                #pragma unroll
                for (int nf = 0; nf < 4; ++nf)
                    acc[mf][nf] = (f32x4){0.f, 0.f, 0.f, 0.f};

            #pragma unroll
            for (int kk = 0; kk < 2; ++kk) {
                const int kb = kt * 64 + kk * 32 + g * 8;
                bf16x8 bh[4], bl[4];
                #pragma unroll
                for (int nf = 0; nf < 4; ++nf) {
                    const size_t roff = (size_t)(j0 + wc * 64 + nf * 16 + cl) * H_DIM + kb;
                    bh[nf] = *(const bf16x8*)(Wh + roff);
                    bl[nf] = *(const bf16x8*)(Wl + roff);
                }
                #pragma unroll
                for (int mf = 0; mf < 4; ++mf)
                    #pragma unroll
                    for (int nf = 0; nf < 4; ++nf) {
                        acc[mf][nf] = __builtin_amdgcn_mfma_f32_16x16x32_bf16(ah[mf][kk], bh[nf], acc[mf][nf], 0, 0, 0);
                        acc[mf][nf] = __builtin_amdgcn_mfma_f32_16x16x32_bf16(ah[mf][kk], bl[nf], acc[mf][nf], 0, 0, 0);
                        acc[mf][nf] = __builtin_amdgcn_mfma_f32_16x16x32_bf16(al[mf][kk], bh[nf], acc[mf][nf], 0, 0, 0);
                    }
            }

            // ---- partial epilogue: rowsum += encprev .* acc, reduce over j ----
            #pragma unroll
            for (int mf = 0; mf < 4; ++mf) {
                float rs0 = 0.f, rs1 = 0.f, rs2 = 0.f, rs3 = 0.f;
                const int growb = m0 + wr * 64 + mf * 16 + g * 4;
                #pragma unroll
                for (int nf = 0; nf < 4; ++nf) {
                    const int gcol = j0 + wc * 64 + nf * 16 + cl;
                    float e0 = (growb + 0 >= B_DIM) ? enc[(size_t)(growb + 0 - B_DIM) * H_DIM + gcol] : 0.f;
                    float e1 = (growb + 1 >= B_DIM) ? enc[(size_t)(growb + 1 - B_DIM) * H_DIM + gcol] : 0.f;
                    float e2 = (growb + 2 >= B_DIM) ? enc[(size_t)(growb + 2 - B_DIM) * H_DIM + gcol] : 0.f;
                    float e3 = (growb + 3 >= B_DIM) ? enc[(size_t)(growb + 3 - B_DIM) * H_DIM + gcol] : 0.f;
                    rs0 += acc[mf][nf][0] * e0;
                    rs1 += acc[mf][nf][1] * e1;
                    rs2 += acc[mf][nf][2] * e2;
                    rs3 += acc[mf][nf][3] * e3;
                }
                #pragma unroll
                for (int off = 1; off < 16; off <<= 1) {
                    rs0 += __shfl_xor(rs0, off);
                    rs1 += __shfl_xor(rs1, off);
                    rs2 += __shfl_xor(rs2, off);
                    rs3 += __shfl_xor(rs3, off);
                }
                if (cl == 0) {
                    const int rb = wr * 64 + mf * 16 + g * 4;
                    rowsum[wc][rb + 0] += rs0;
                    rowsum[wc][rb + 1] += rs1;
                    rowsum[wc][rb + 2] += rs2;
                    rowsum[wc][rb + 3] += rs3;
                }
            }
        }
    }

    __syncthreads();
    if (tid < 128) {
        const int gm = m0 + tid;
        if (gm >= B_DIM) {
            // transposed: L[b*S + s]
            L[(size_t)(gm & 31) * S_DIM + (gm >> 5)] = rowsum[0][tid] + rowsum[1][tid];
        }
    }
}

// ---------------------------------------------------------------------------
// Kernel 3: per-b softmax over s, plus affect term and the s=0 logit.
// L is transposed: L[b*S + s] (coalesced reads). 1024 threads/block.
// ---------------------------------------------------------------------------
__global__ __launch_bounds__(1024) void softmax_kernel(
    const float* __restrict__ enc,
    const float* __restrict__ hid,
    const float* __restrict__ emb,
    const float* __restrict__ aff,
    const float* __restrict__ L,
    float* __restrict__ out)
{
    __shared__ float logits[S_DIM];
    __shared__ float wred[16][4];
    __shared__ float bcast[4];
    __shared__ float wtmp[16];

    const int b    = blockIdx.x;
    const int tid  = threadIdx.x;
    const int wave = tid >> 6;
    const int lane = tid & 63;

    // ha[k] = sum_h hid[b,h]*aff[h,k];  s0 = sum_h enc[0,b,h]*hid[b,h]
    float p0 = 0.f, p1 = 0.f, p2 = 0.f, p3 = 0.f;
    if (tid < H_DIM) {
        const int h = tid;
        const float hv = hid[b * H_DIM + h];
        p0 = hv * aff[h * 3 + 0];
        p1 = hv * aff[h * 3 + 1];
        p2 = hv * aff[h * 3 + 2];
        p3 = hv * enc[(size_t)b * H_DIM + h];
    }
    #pragma unroll
    for (int off = 32; off > 0; off >>= 1) {
        p0 += __shfl_down(p0, off);
        p1 += __shfl_down(p1, off);
        p2 += __shfl_down(p2, off);
        p3 += __shfl_down(p3, off);
    }
    if (lane == 0) { wred[wave][0] = p0; wred[wave][1] = p1; wred[wave][2] = p2; wred[wave][3] = p3; }
    __syncthreads();
    if (tid < 4) {
        float s = 0.f;
        #pragma unroll
        for (int w = 0; w < 16; ++w) s += wred[w][tid];
        bcast[tid] = s;
    }
    __syncthreads();
    const float ha0 = bcast[0], ha1 = bcast[1], ha2 = bcast[2], s0dot = bcast[3];

    float mx = -3.4e38f;
    #pragma unroll
    for (int it = 0; it < 4; ++it) {
        const int s = tid + it * 1024;
        const float ed = (s == 0) ? s0dot : L[(size_t)b * S_DIM + s];
        const float* e = emb + (size_t)(s * B_DIM + b) * 3;
        const float lg = ed + ha0 * e[0] + ha1 * e[1] + ha2 * e[2];
        logits[s] = lg;
        mx = fmaxf(mx, lg);
    }
    #pragma unroll
    for (int off = 32; off > 0; off >>= 1) mx = fmaxf(mx, __shfl_xor(mx, off));
    if (lane == 0) wtmp[wave] = mx;
    __syncthreads();
    mx = wtmp[0];
    #pragma unroll
    for (int w = 1; w < 16; ++w) mx = fmaxf(mx, wtmp[w]);
    __syncthreads();

    float sum = 0.f;
    #pragma unroll
    for (int it = 0; it < 4; ++it) {
        const int s = tid + it * 1024;
        const float ex = __expf(logits[s] - mx);
        logits[s] = ex;
        sum += ex;
    }
    #pragma unroll
    for (int off = 32; off > 0; off >>= 1) sum += __shfl_xor(sum, off);
    if (lane == 0) wtmp[wave] = sum;
    __syncthreads();
    sum = 0.f;
    #pragma unroll
    for (int w = 0; w < 16; ++w) sum += wtmp[w];
    const float inv = 1.0f / sum;
    #pragma unroll
    for (int it = 0; it < 4; ++it) {
        const int s = tid + it * 1024;
        out[(size_t)b * S_DIM + s] = logits[s] * inv;
    }
}

// ---------------------------------------------------------------------------
extern "C" void kernel_launch(void* const* d_in, const int* in_sizes, int n_in,
                              void* d_out, int out_size, void* d_ws, size_t ws_size,
                              hipStream_t stream) {
    const float* hid = (const float*)d_in[0];   // [1,B,H]
    const float* enc = (const float*)d_in[1];   // [S,B,H]
    const float* emb = (const float*)d_in[2];   // [S,B,3]
    const float* Wm  = (const float*)d_in[3];   // [H,H]
    const float* aff = (const float*)d_in[4];   // [H,3]
    float* out = (float*)d_out;                 // [B,1,S]

    char* ws = (char*)d_ws;
    u16*   Wh = (u16*)(ws);                     // 512 KB
    u16*   Wl = (u16*)(ws + (512u << 10));      // 512 KB
    float* L  = (float*)(ws + (1024u << 10));   // 512 KB (transposed: L[b*S+s])

    hipLaunchKernelGGL(prep_w,         dim3(1024), dim3(256),  0, stream, Wm, Wh, Wl);
    hipLaunchKernelGGL(bigram_gemm,    dim3(1024), dim3(256),  0, stream, enc, hid, Wh, Wl, L);
    hipLaunchKernelGGL(softmax_kernel, dim3(32),   dim3(1024), 0, stream, enc, hid, emb, aff, L, out);
}